// Round 10
// baseline (1517.259 us; speedup 1.0000x reference)
//
#include <hip/hip_runtime.h>
#include <hip/hip_fp16.h>
#include <math.h>

#define B_ 8
#define T_ 32
#define N_ 10000
#define F_ 16
#define E_ 160000
#define HG_ 64
#define HT_ 128
#define BT_ (B_*T_)
#define PB_ 157   // ceil(N/64) node-chunks per bt
#define EPS_ 1e-5f
#define NR_ (N_+1)   // +1 phantom zero row for branch-free gathers

typedef __attribute__((ext_vector_type(8))) _Float16 f16x8_t;  // 8 f16 = 4 VGPRs
typedef __attribute__((ext_vector_type(4))) float f32x4_t;     // MFMA acc / nt loads
typedef __attribute__((ext_vector_type(4))) unsigned uint4v;   // nt gather loads

__device__ inline unsigned short f2h(float f) {
  return __half_as_ushort(__float2half(f));
}
__device__ inline unsigned pkrtz_u(float a, float b) {
  auto h = __builtin_amdgcn_cvt_pkrtz(a, b);
  unsigned u; __builtin_memcpy(&u, &h, 4); return u;
}
__device__ inline unsigned pack2h(float a, float b) {
  __half2 h = __floats2half2_rn(a, b);
  unsigned u; __builtin_memcpy(&u, &h, 4); return u;
}
__device__ inline __half2 u2h(unsigned u) {
  __half2 h; __builtin_memcpy(&h, &u, 4); return h;
}
__device__ inline unsigned h2u(__half2 h) {
  unsigned u; __builtin_memcpy(&u, &h, 4); return u;
}
__device__ inline void bflyh(__half2& a, int m) {
  unsigned u = (unsigned)__shfl_xor((int)h2u(a), m);
  a += u2h(u);
}

// ---------------- CSR build ----------------
__global__ void k_zero(int* p, int n) {
  int i = blockIdx.x * 256 + threadIdx.x;
  if (i < n) p[i] = 0;
}

__global__ void k_deg(const int* __restrict__ dst, int* __restrict__ deg) {
  int e = blockIdx.x * 256 + threadIdx.x;
  if (e < E_) atomicAdd(&deg[dst[e]], 1);
}

__global__ void k_scan(const int* __restrict__ deg, int* __restrict__ row_ptr,
                       float* __restrict__ inv_deg) {
  __shared__ int part[256];
  int tid = threadIdx.x;
  int base = tid * 40;
  int s = 0;
  for (int i = 0; i < 40; i++) { int idx = base + i; if (idx < N_) s += deg[idx]; }
  part[tid] = s;
  __syncthreads();
  if (tid == 0) {
    int run = 0;
    for (int i = 0; i < 256; i++) { int v = part[i]; part[i] = run; run += v; }
  }
  __syncthreads();
  int run = part[tid];
  for (int i = 0; i < 40; i++) {
    int idx = base + i;
    if (idx < N_) {
      row_ptr[idx] = run;
      int d = deg[idx];
      run += d;
      inv_deg[idx] = 1.0f / fmaxf((float)d, 1.0f);
    } else if (idx == N_) {
      row_ptr[N_] = run;
    }
  }
}

__global__ void k_fill(const int* __restrict__ src, const int* __restrict__ dst,
                       const int* __restrict__ row_ptr, int* __restrict__ cursor,
                       int* __restrict__ col) {
  int e = blockIdx.x * 256 + threadIdx.x;
  if (e < E_) {
    int d = dst[e];
    int p = atomicAdd(&cursor[d], 1);
    col[row_ptr[d] + p] = src[e];
  }
}

// ---------------- weight prep (f16 fragments) ----------------
__global__ void k_prepw(const float* __restrict__ W2l, const float* __restrict__ W2r,
                        unsigned short* __restrict__ Wbf) {
  int idx = blockIdx.x * 256 + threadIdx.x;   // 8192 total
  if (idx >= 4 * 4 * 64 * 8) return;
  int q  = idx & 7;
  int l  = (idx >> 3) & 63;
  int ks = (idx >> 9) & 3;
  int w  = idx >> 11;
  int j = w * 16 + (l & 15);
  int k = ks * 32 + ((l >> 4) * 8) + q;
  float v = (k < 64) ? W2l[j * 64 + k] : W2r[j * 64 + (k - 64)];
  Wbf[idx] = f2h(v);
}

__global__ void k_prepw1(const float* __restrict__ W1l, const float* __restrict__ W1r,
                         unsigned short* __restrict__ Wb1) {
  int idx = blockIdx.x * 256 + threadIdx.x;   // 2048 total
  if (idx >= 4 * 64 * 8) return;
  int q = idx & 7;
  int l = (idx >> 3) & 63;
  int w = idx >> 9;
  int j = w * 16 + (l & 15);
  int k = ((l >> 4) * 8) + q;
  float v = (k < 16) ? W1l[j * 16 + k] : W1r[j * 16 + (k - 16)];
  Wb1[idx] = f2h(v);
}

// ---------------- SAGE layer 1, MFMA Phase B, f16 ----------------
// Phase A: lane = (node[2] | eo2[2] | fq2[2]); nt float4 gathers; staged
// row_ptr; 4-deep unrolled rounds (pad via zero row, exact +0.0).
__launch_bounds__(256, 8)
__global__ void k_sage1t(const float* __restrict__ x, const int* __restrict__ row_ptr,
                         const int* __restrict__ col, const float* __restrict__ inv_deg,
                         const unsigned short* __restrict__ Wb1, const float* __restrict__ b1,
                         const float* __restrict__ g1, const float* __restrict__ be1,
                         unsigned short* __restrict__ h1, const float* __restrict__ zrow,
                         int bt0, int CH, int swz) {
  __shared__ __align__(16) unsigned short ZU[64 * 136];   // f16 Z1b[64][40] / f32 Zf[64][68]
  __shared__ float red[2][4][64];
  unsigned short* Z1b = ZU;
  float* Zf = (float*)ZU;
  int i = blockIdx.x;
  int btl, chunk;
  if (swz) {  // pin all blocks of one bt to one XCD
    int xcd = i & 7; int j = i >> 3; int per = CH >> 3;
    btl = xcd * per + j / PB_; chunk = j % PB_;
  } else {
    btl = i / PB_; chunk = i % PB_;
  }
  int bt = bt0 + btl;
  size_t xbase = (size_t)bt * (N_ * F_);
  int tid = threadIdx.x;
  int w = __builtin_amdgcn_readfirstlane(tid >> 6);
  int lane = tid & 63;
  int n0 = chunk * 64;
  int node = lane >> 4;        // 0..3
  int eo2 = (lane >> 2) & 3;   // edge slot
  int fq2 = lane & 3;          // feat group (float4)
  const float4* xb = (const float4*)(x + xbase);   // node row = 4 float4
  const f32x4_t* x4b = (const f32x4_t*)(x + xbase);
  const f32x4_t* z4 = (const f32x4_t*)zrow;

  // ---- stage row_ptr / deg / inv_deg for this wave's 16 nodes ----
  int nloc = n0 + w * 16 + (lane & 15);
  int rpA = 0, dS = 0; float ivS = 0.f;
  if (nloc < N_) { rpA = row_ptr[nloc]; dS = row_ptr[nloc + 1] - rpA; ivS = inv_deg[nloc]; }

  // ---- Phase A ----
  for (int p = 0; p < 4; ++p) {
    int mA = w * 16 + p * 4;
    int nA = n0 + mA;
    int s0My   = __shfl(rpA, p * 4 + node);
    int dMy    = __shfl(dS,  p * 4 + node);
    float ivMy = __shfl(ivS, p * 4 + node);
    int dcMy = dMy > 64 ? 64 : dMy;
    int tmx = max(dcMy, __shfl_xor(dcMy, 16));
    int mx  = max(tmx, __shfl_xor(tmx, 32));
    int rounds = (mx + 3) >> 2;
    // stage my node's col list: 4 regs x 16 entries (each reg = 4 rounds)
    int pos = lane & 15;
    int c0r = (pos      < dMy) ? col[s0My + pos]      : 0;
    int c1r = (pos + 16 < dMy) ? col[s0My + pos + 16] : 0;
    int c2r = (pos + 32 < dMy) ? col[s0My + pos + 32] : 0;
    int c3r = (pos + 48 < dMy) ? col[s0My + pos + 48] : 0;
    float4 a = {0.f, 0.f, 0.f, 0.f};
#define S1B(REG, BASE, RR)                                             \
    {                                                                  \
      int idx = eo2 + 4 * (RR);                                        \
      int s = __shfl(REG, (lane & 48) | (idx - (BASE)));               \
      const f32x4_t* bp = (idx < dcMy) ? (x4b + (size_t)s * 4) : z4;   \
      f32x4_t v = __builtin_nontemporal_load(bp + fq2);                \
      a.x += v.x; a.y += v.y; a.z += v.z; a.w += v.w;                  \
    }
    int rounds4 = (rounds + 3) & ~3;
    int r = 0;
    for (; r < rounds4 && r < 4;  r += 4) { S1B(c0r, 0, r)  S1B(c0r, 0, r + 1)  S1B(c0r, 0, r + 2)  S1B(c0r, 0, r + 3) }
    for (; r < rounds4 && r < 8;  r += 4) { S1B(c1r, 16, r) S1B(c1r, 16, r + 1) S1B(c1r, 16, r + 2) S1B(c1r, 16, r + 3) }
    for (; r < rounds4 && r < 12; r += 4) { S1B(c2r, 32, r) S1B(c2r, 32, r + 1) S1B(c2r, 32, r + 2) S1B(c2r, 32, r + 3) }
    for (; r < rounds4; r += 4)           { S1B(c3r, 48, r) S1B(c3r, 48, r + 1) S1B(c3r, 48, r + 2) S1B(c3r, 48, r + 3) }
#undef S1B
    if (dMy > 64) {
      for (int e = s0My + 64; e < s0My + dMy; ++e) {
        if (eo2 == 0) {
          float4 v = xb[(size_t)col[e] * 4 + fq2];
          a.x += v.x; a.y += v.y; a.z += v.z; a.w += v.w;
        }
      }
    }
    // butterfly over eo2 (lane bits 2-3)
    a.x += __shfl_xor(a.x, 4);  a.y += __shfl_xor(a.y, 4);
    a.z += __shfl_xor(a.z, 4);  a.w += __shfl_xor(a.w, 4);
    a.x += __shfl_xor(a.x, 8);  a.y += __shfl_xor(a.y, 8);
    a.z += __shfl_xor(a.z, 8);  a.w += __shfl_xor(a.w, 8);
    if (eo2 == 0) {
      uint2 pk;
      pk.x = pkrtz_u(a.x * ivMy, a.y * ivMy);
      pk.y = pkrtz_u(a.z * ivMy, a.w * ivMy);
      *(uint2*)&Z1b[(mA + node) * 40 + fq2 * 4] = pk;          // agg: k = fq2*4..+3
    } else if (eo2 == 1) {
      int nS = nA + node;
      float4 sv = {0.f, 0.f, 0.f, 0.f};
      if (nS < N_) sv = xb[(size_t)nS * 4 + fq2];
      uint2 pk;
      pk.x = pkrtz_u(sv.x, sv.y);
      pk.y = pkrtz_u(sv.z, sv.w);
      *(uint2*)&Z1b[(mA + node) * 40 + 16 + fq2 * 4] = pk;     // self: k = 16+..
    }
  }
  __syncthreads();

  // ---- Phase B: one f16 MFMA per node-tile. Wave w owns j in [16w,16w+16). ----
  int g = lane >> 4, c = lane & 15;
  float bj = b1[w * 16 + c];
  f32x4_t accf[4];
#pragma unroll
  for (int mt = 0; mt < 4; ++mt) accf[mt] = (f32x4_t){bj, bj, bj, bj};
  f16x8_t bfr = ((const f16x8_t*)Wb1)[w * 64 + lane];
#pragma unroll
  for (int mt = 0; mt < 4; ++mt) {
    const f16x8_t* ap = (const f16x8_t*)&Z1b[(mt * 16 + c) * 40 + g * 8];
    accf[mt] = __builtin_amdgcn_mfma_f32_16x16x32_f16(*ap, bfr, accf[mt], 0, 0, 0);
  }
  __syncthreads();   // all waves done reading Z1b before aliased fp32 writes

  // C layout (HW-verified, dtype-independent): col = lane&15, row = 4*(lane>>4)+reg.
#pragma unroll
  for (int mt = 0; mt < 4; ++mt) {
#pragma unroll
    for (int q = 0; q < 4; ++q) {
      int nodeq = mt * 16 + g * 4 + q;
      Zf[nodeq * 68 + w * 16 + c] = accf[mt][q];
    }
  }
  __syncthreads();

  // ---- Epilogue: lane = node m; wave w owns j-quarter [16w,16w+16) ----
  int m = lane;
  const float* zr = Zf + m * 68 + w * 16;
  float4 z0 = *(const float4*)(zr + 0);
  float4 z1 = *(const float4*)(zr + 4);
  float4 z2 = *(const float4*)(zr + 8);
  float4 z3 = *(const float4*)(zr + 12);
  float acc[16];
  acc[0] = z0.x; acc[1] = z0.y; acc[2] = z0.z; acc[3] = z0.w;
  acc[4] = z1.x; acc[5] = z1.y; acc[6] = z1.z; acc[7] = z1.w;
  acc[8] = z2.x; acc[9] = z2.y; acc[10] = z2.z; acc[11] = z2.w;
  acc[12] = z3.x; acc[13] = z3.y; acc[14] = z3.z; acc[15] = z3.w;

  // ---- LayerNorm across j (single-pass: sum + sumsq) ----
  float s1 = 0.f, s2 = 0.f;
#pragma unroll
  for (int jj = 0; jj < 16; ++jj) { s1 += acc[jj]; s2 += acc[jj] * acc[jj]; }
  red[0][w][m] = s1;
  red[1][w][m] = s2;
  __syncthreads();
  float mu = (red[0][0][m] + red[0][1][m] + red[0][2][m] + red[0][3][m]) * (1.f / 64.f);
  float ex2 = (red[1][0][m] + red[1][1][m] + red[1][2][m] + red[1][3][m]) * (1.f / 64.f);
  float var = fmaxf(ex2 - mu * mu, 0.f);
  float rs = rsqrtf(var + EPS_);

  // ---- relu + f16 pack + store (h1 has NR_=N+1 rows; row N_ = phantom) ----
  int nAbs = n0 + m;
  unsigned short* dst = h1 + ((size_t)btl * NR_ + nAbs) * HG_ + w * 16;
  if (nAbs < N_) {
#pragma unroll
    for (int jj = 0; jj < 16; ++jj)
      acc[jj] = fmaxf((acc[jj] - mu) * rs * g1[w * 16 + jj] + be1[w * 16 + jj], 0.f);
    uint4 pa, pb;
    pa.x = pack2h(acc[0], acc[1]);  pa.y = pack2h(acc[2], acc[3]);
    pa.z = pack2h(acc[4], acc[5]);  pa.w = pack2h(acc[6], acc[7]);
    pb.x = pack2h(acc[8], acc[9]);  pb.y = pack2h(acc[10], acc[11]);
    pb.z = pack2h(acc[12], acc[13]); pb.w = pack2h(acc[14], acc[15]);
    *(uint4*)dst = pa;
    *(uint4*)(dst + 8) = pb;
  } else if (nAbs == N_) {
    uint4 zz = {0, 0, 0, 0};
    *(uint4*)dst = zz;
    *(uint4*)(dst + 8) = zz;
  }
}

// ---------------- SAGE layer 2 (f16 in), MFMA Phase B ----------------
// Phase A: lane = (nsel[1] | eo2[2] | fq3[3]); nt uint4 gathers; staged
// row_ptr; ALL col lists pre-staged; 4-deep unrolled rounds (pad via phantom
// row, exact +0.0); packed __half2 accumulate.
__launch_bounds__(256, 8)
__global__ void k_sage2t(const unsigned short* __restrict__ h1, const int* __restrict__ row_ptr,
                         const int* __restrict__ col, const float* __restrict__ inv_deg,
                         const unsigned short* __restrict__ Wbf, const float* __restrict__ b2,
                         const float* __restrict__ g2, const float* __restrict__ be2,
                         float* __restrict__ Hsum, int bt0, int CH, int swz) {
  __shared__ __align__(16) unsigned short Zb[64 * 136];   // f16 / aliased fp32
  __shared__ float red[2][4][64];
  float* Zf = (float*)Zb;   // fp32 view, stride 68 floats
  int i = blockIdx.x;
  int btl, chunk;
  if (swz) {
    int xcd = i & 7; int j = i >> 3; int per = CH >> 3;
    btl = xcd * per + j / PB_; chunk = j % PB_;
  } else {
    btl = i / PB_; chunk = i % PB_;
  }
  int bt = bt0 + btl;
  int b = bt / T_, t = bt % T_;
  const char* h8c = (const char*)(h1 + (size_t)btl * (NR_ * HG_));  // row = 128 B
  int tid = threadIdx.x;
  int w = __builtin_amdgcn_readfirstlane(tid >> 6);
  int lane = tid & 63;
  int n0 = chunk * 64;
  int nsel = lane >> 5;        // 0/1: which of the pair's nodes
  int eo2 = (lane >> 3) & 3;   // 4 edge slots
  int fq3 = lane & 7;          // 8 feat groups (uint4 = 8 f16)
  unsigned foff = (unsigned)fq3 * 16;
  int pos = lane & 31;

  // ---- stage row_ptr / deg / inv_deg for this wave's 16 nodes ----
  int nloc = n0 + w * 16 + (lane & 15);
  int rpA = 0, dS = 0; float ivS = 0.f;
  if (nloc < N_) { rpA = row_ptr[nloc]; dS = row_ptr[nloc + 1] - rpA; ivS = inv_deg[nloc]; }

  // ---- pre-stage ALL 8 p-iters' col lists (16 independent loads in flight) ----
  int cp0[8], cp1[8];
#pragma unroll
  for (int p = 0; p < 8; ++p) {
    int s0 = __shfl(rpA, p * 2 + nsel);
    int d  = __shfl(dS,  p * 2 + nsel);
    cp0[p] = (pos      < d) ? col[s0 + pos]      : N_;
    cp1[p] = (pos + 32 < d) ? col[s0 + pos + 32] : N_;
  }

  // ---- Phase A ----
#pragma unroll
  for (int p = 0; p < 8; ++p) {
    int mA = w * 16 + p * 2;
    int s0My   = __shfl(rpA, p * 2 + nsel);
    int dMy    = __shfl(dS,  p * 2 + nsel);
    float ivMy = __shfl(ivS, p * 2 + nsel);
    int dcMy = dMy > 64 ? 64 : dMy;
    int mx = max(dcMy, __shfl_xor(dcMy, 32));
    int rounds = (mx + 3) >> 2;
    __half2 a0 = __float2half2_rn(0.f), a1 = a0, a2 = a0, a3 = a0;
#define S2B(PREG, BASE, RR)                                             \
    {                                                                   \
      int idx = eo2 + 4 * (RR);                                         \
      int s = __shfl(PREG, (lane & 32) | (idx - (BASE)));               \
      uint4v v = __builtin_nontemporal_load(                            \
          (const uint4v*)(h8c + (((unsigned)s << 7) + foff)));          \
      a0 += u2h(v.x); a1 += u2h(v.y); a2 += u2h(v.z); a3 += u2h(v.w);   \
    }
    int rounds4 = (rounds + 3) & ~3;
    int r = 0;
    for (; r < rounds4 && r < 8; r += 4) { S2B(cp0[p], 0, r)  S2B(cp0[p], 0, r + 1)  S2B(cp0[p], 0, r + 2)  S2B(cp0[p], 0, r + 3) }
    for (; r < rounds4; r += 4)          { S2B(cp1[p], 32, r) S2B(cp1[p], 32, r + 1) S2B(cp1[p], 32, r + 2) S2B(cp1[p], 32, r + 3) }
#undef S2B
    if (dMy > 64) {
      for (int e = s0My + 64; e < s0My + dMy; ++e) {
        if (eo2 == 0) {
          uint4 v = *(const uint4*)(h8c + (((unsigned)col[e] << 7) + foff));
          a0 += u2h(v.x); a1 += u2h(v.y); a2 += u2h(v.z); a3 += u2h(v.w);
        }
      }
    }
    // butterfly over eo2 (lane bits 3-4), packed f16
    bflyh(a0, 8);  bflyh(a1, 8);  bflyh(a2, 8);  bflyh(a3, 8);
    bflyh(a0, 16); bflyh(a1, 16); bflyh(a2, 16); bflyh(a3, 16);
    if (eo2 == 0) {
      __half2 ivh = __float2half2_rn(ivMy);
      uint4 pk;
      pk.x = h2u(a0 * ivh); pk.y = h2u(a1 * ivh);
      pk.z = h2u(a2 * ivh); pk.w = h2u(a3 * ivh);
      *(uint4*)&Zb[(mA + nsel) * 136 + fq3 * 8] = pk;            // agg: k = fq3*8..+7
    } else if (eo2 == 1) {
      int nA = n0 + mA;
      int nS = nA + nsel;
      int nSc = nS < N_ ? nS : N_;
      uint4 sv = *(const uint4*)(h8c + (((unsigned)nSc << 7) + foff));
      *(uint4*)&Zb[(mA + nsel) * 136 + 64 + fq3 * 8] = sv;       // self: k = 64+..
    }
  }
  __syncthreads();

  // ---- Phase B: f16 MFMA. Wave w owns output features j in [16w, 16w+16). ----
  int g = lane >> 4, c = lane & 15;
  const f16x8_t* Wb8 = (const f16x8_t*)Wbf;
  float bj = b2[w * 16 + c];
  f32x4_t accf[4];
#pragma unroll
  for (int mt = 0; mt < 4; ++mt) accf[mt] = (f32x4_t){bj, bj, bj, bj};
#pragma unroll
  for (int ks = 0; ks < 4; ++ks) {
    f16x8_t bfr = Wb8[(w * 4 + ks) * 64 + lane];
#pragma unroll
    for (int mt = 0; mt < 4; ++mt) {
      const f16x8_t* ap = (const f16x8_t*)&Zb[(mt * 16 + c) * 136 + ks * 32 + g * 8];
      accf[mt] = __builtin_amdgcn_mfma_f32_16x16x32_f16(*ap, bfr, accf[mt], 0, 0, 0);
    }
  }
  __syncthreads();   // all waves done reading Zb before aliased fp32 writes

  // C layout (HW-verified): col = lane&15, row = 4*(lane>>4)+reg.
#pragma unroll
  for (int mt = 0; mt < 4; ++mt) {
#pragma unroll
    for (int q = 0; q < 4; ++q) {
      int nodeq = mt * 16 + g * 4 + q;
      Zf[nodeq * 68 + w * 16 + c] = accf[mt][q];
    }
  }
  __syncthreads();

  // ---- Epilogue: lane = node m; wave w owns j-quarter [16w,16w+16) ----
  int m = lane;
  float* zr = Zf + m * 68 + w * 16;
  float4 z0 = *(const float4*)(zr + 0);
  float4 z1 = *(const float4*)(zr + 4);
  float4 z2 = *(const float4*)(zr + 8);
  float4 z3 = *(const float4*)(zr + 12);
  float acc[16];
  acc[0] = z0.x; acc[1] = z0.y; acc[2] = z0.z; acc[3] = z0.w;
  acc[4] = z1.x; acc[5] = z1.y; acc[6] = z1.z; acc[7] = z1.w;
  acc[8] = z2.x; acc[9] = z2.y; acc[10] = z2.z; acc[11] = z2.w;
  acc[12] = z3.x; acc[13] = z3.y; acc[14] = z3.z; acc[15] = z3.w;

  // ---- LayerNorm across j (single-pass: sum + sumsq) ----
  float s1 = 0.f, s2 = 0.f;
#pragma unroll
  for (int jj = 0; jj < 16; ++jj) { s1 += acc[jj]; s2 += acc[jj] * acc[jj]; }
  red[0][w][m] = s1;
  red[1][w][m] = s2;
  __syncthreads();
  float mu = (red[0][0][m] + red[0][1][m] + red[0][2][m] + red[0][3][m]) * (1.f / 64.f);
  float ex2 = (red[1][0][m] + red[1][1][m] + red[1][2][m] + red[1][3][m]) * (1.f / 64.f);
  float var = fmaxf(ex2 - mu * mu, 0.f);
  float rs = rsqrtf(var + EPS_);

  // ---- relu, write back in-place (lane-exclusive region: no hazard) ----
  bool okm = (n0 + m) < N_;
#pragma unroll
  for (int jj = 0; jj < 16; ++jj) {
    float hv = fmaxf((acc[jj] - mu) * rs * g2[w * 16 + jj] + be2[w * 16 + jj], 0.f);
    acc[jj] = okm ? hv : 0.f;
  }
  float4 o0 = {acc[0], acc[1], acc[2], acc[3]};
  float4 o1 = {acc[4], acc[5], acc[6], acc[7]};
  float4 o2 = {acc[8], acc[9], acc[10], acc[11]};
  float4 o3 = {acc[12], acc[13], acc[14], acc[15]};
  *(float4*)(zr + 0) = o0;  *(float4*)(zr + 4) = o1;
  *(float4*)(zr + 8) = o2;  *(float4*)(zr + 12) = o3;
  __syncthreads();

  // ---- column sums: lane = feature j; wave w sums rows [16w,16w+16) ----
  float cs = 0.f;
#pragma unroll
  for (int ii = 0; ii < 16; ++ii) cs += Zf[(w * 16 + ii) * 68 + lane];
  red[0][w][lane] = cs;
  __syncthreads();
  if (w == 0) {
    float tot = red[0][0][lane] + red[0][1][lane] + red[0][2][lane] + red[0][3][lane];
    atomicAdd(&Hsum[(t * B_ + b) * HG_ + lane], tot);
  }
}

// ---------------- GRU input precompute: GI[t][b][384] ----------------
__global__ void k_gi(const float* __restrict__ Hsum, const float* __restrict__ W_ih,
                     const float* __restrict__ b_ih, float* __restrict__ GI) {
  __shared__ float xv[64];
  int tb = blockIdx.x;
  int tid = threadIdx.x;
  if (tid < 64) xv[tid] = Hsum[tb * 64 + tid] * (1.0f / (float)N_);
  __syncthreads();
  float g = b_ih[tid];
  const float4* W4 = (const float4*)(W_ih + tid * 64);
  const float4* x4 = (const float4*)xv;
#pragma unroll
  for (int q = 0; q < 16; q++) {
    float4 w = W4[q], xq = x4[q];
    g = fmaf(xq.x, w.x, g); g = fmaf(xq.y, w.y, g);
    g = fmaf(xq.z, w.z, g); g = fmaf(xq.w, w.w, g);
  }
  GI[tb * 384 + tid] = g;
}

// ---------------- sequential GRU + head; one block per batch ----------------
__global__ void k_gru(const float* __restrict__ GI, const float* __restrict__ W_hh,
                      const float* __restrict__ b_hh, const float* __restrict__ Wh,
                      const float* __restrict__ bh, float* __restrict__ out) {
  __shared__ float hL[128];
  __shared__ float ghL[384];
  __shared__ float red[128];
  int b = blockIdx.x, tid = threadIdx.x;
  if (tid < 128) hL[tid] = 0.f;
  float bhh = b_hh[tid];
  const float4* W4 = (const float4*)(W_hh + tid * 128);
  for (int t = 0; t < T_; ++t) {
    __syncthreads();
    float g = bhh;
    const float4* h4 = (const float4*)hL;
#pragma unroll
    for (int q = 0; q < 32; q++) {
      float4 w = W4[q], hv = h4[q];
      g = fmaf(hv.x, w.x, g); g = fmaf(hv.y, w.y, g);
      g = fmaf(hv.z, w.z, g); g = fmaf(hv.w, w.w, g);
    }
    ghL[tid] = g;
    __syncthreads();
    float hnew = 0.f;
    if (tid < 128) {
      const float* gi = GI + (t * B_ + b) * 384;
      float rr = 1.f / (1.f + expf(-(gi[tid] + ghL[tid])));
      float zz = 1.f / (1.f + expf(-(gi[128 + tid] + ghL[128 + tid])));
      float nn = tanhf(gi[256 + tid] + rr * ghL[256 + tid]);
      hnew = (1.f - zz) * nn + zz * hL[tid];
    }
    __syncthreads();
    if (tid < 128) hL[tid] = hnew;
  }
  __syncthreads();
  if (tid < 128) red[tid] = hL[tid] * Wh[tid];
  __syncthreads();
  if (tid == 0) {
    float s = bh[0];
    for (int k = 0; k < 128; k++) s += red[k];
    out[b] = s;
  }
}

extern "C" void kernel_launch(void* const* d_in, const int* in_sizes, int n_in,
                              void* d_out, int out_size, void* d_ws, size_t ws_size,
                              hipStream_t stream) {
  const float* x    = (const float*)d_in[0];
  const int*   ei   = (const int*)d_in[1];
  const float* W1l  = (const float*)d_in[2];
  const float* b1   = (const float*)d_in[3];
  const float* W1r  = (const float*)d_in[4];
  const float* g1   = (const float*)d_in[5];
  const float* be1  = (const float*)d_in[6];
  const float* W2l  = (const float*)d_in[7];
  const float* b2   = (const float*)d_in[8];
  const float* W2r  = (const float*)d_in[9];
  const float* g2   = (const float*)d_in[10];
  const float* be2  = (const float*)d_in[11];
  const float* W_ih = (const float*)d_in[12];
  const float* W_hh = (const float*)d_in[13];
  const float* b_ih = (const float*)d_in[14];
  const float* b_hh = (const float*)d_in[15];
  const float* Wh   = (const float*)d_in[16];
  const float* bh   = (const float*)d_in[17];
  float* out = (float*)d_out;

  char* ws = (char*)d_ws;
  size_t off = 0;
  auto alloc = [&](size_t bytes) { void* p = ws + off; off += (bytes + 255) & ~(size_t)255; return p; };
  int*   deg     = (int*)alloc((size_t)N_ * 4);
  int*   row_ptr = (int*)alloc((size_t)(N_ + 1) * 4);
  int*   cursor  = (int*)alloc((size_t)N_ * 4);
  int*   col     = (int*)alloc((size_t)E_ * 4);
  float* ivd     = (float*)alloc((size_t)N_ * 4);
  float* Hsum    = (float*)alloc((size_t)BT_ * HG_ * 4);
  float* GI      = (float*)alloc((size_t)BT_ * 384 * 4);
  unsigned short* Wbf = (unsigned short*)alloc((size_t)4 * 4 * 64 * 8 * 2);  // sage2 f16 B-frags
  unsigned short* Wb1 = (unsigned short*)alloc((size_t)4 * 64 * 8 * 2);      // sage1 f16 B-frags
  float* zrowp   = (float*)alloc(256);   // 128B zero row (+ pad), zeroed by k_zero
  size_t fixed = off;
  unsigned short* h1 = (unsigned short*)(ws + off);

  size_t cap = (ws_size > fixed) ? (ws_size - fixed) : 0;
  int CH = (int)(cap / ((size_t)NR_ * HG_ * 2));   // f16 h1, N+1 rows per bt
  if (CH > 64) CH = 64;    // keep chunk working set inside the 256MB L3
  if (CH >= 8) CH &= ~7;   // multiple of 8 for XCD swizzle
  if (CH < 1) CH = 1;

  int zn = (int)(fixed / 4);
  k_zero<<<(zn + 255) / 256, 256, 0, stream>>>((int*)ws, zn);

  const int* srcp = ei;
  const int* dstp = ei + E_;
  k_deg<<<(E_ + 255) / 256, 256, 0, stream>>>(dstp, deg);
  k_scan<<<1, 256, 0, stream>>>(deg, row_ptr, ivd);
  k_fill<<<(E_ + 255) / 256, 256, 0, stream>>>(srcp, dstp, row_ptr, cursor, col);
  k_prepw<<<32, 256, 0, stream>>>(W2l, W2r, Wbf);
  k_prepw1<<<8, 256, 0, stream>>>(W1l, W1r, Wb1);

  for (int bt0 = 0; bt0 < BT_; bt0 += CH) {
    int c = BT_ - bt0 < CH ? BT_ - bt0 : CH;
    int swz = (c % 8 == 0) ? 1 : 0;
    k_sage1t<<<c * PB_, 256, 0, stream>>>(x, row_ptr, col, ivd, Wb1, b1, g1, be1,
                                          h1, zrowp, bt0, c, swz);
    k_sage2t<<<c * PB_, 256, 0, stream>>>(h1, row_ptr, col, ivd, Wbf, b2, g2, be2,
                                          Hsum, bt0, c, swz);
  }
  k_gi<<<BT_, 384, 0, stream>>>(Hsum, W_ih, b_ih, GI);
  k_gru<<<B_, 384, 0, stream>>>(GI, W_hh, b_hh, Wh, bh, out);
}

// Round 11
// 1162.905 us; speedup vs baseline: 1.3047x; 1.3047x over previous
//
#include <hip/hip_runtime.h>
#include <hip/hip_fp16.h>
#include <math.h>

#define B_ 8
#define T_ 32
#define N_ 10000
#define F_ 16
#define E_ 160000
#define HG_ 64
#define HT_ 128
#define BT_ (B_*T_)
#define PB_ 157   // ceil(N/64) node-chunks per bt
#define EPS_ 1e-5f
#define NR_ (N_+1)   // +1 phantom zero row for branch-free gathers

typedef __attribute__((ext_vector_type(8))) _Float16 f16x8_t;  // 8 f16 = 4 VGPRs
typedef __attribute__((ext_vector_type(4))) float f32x4_t;     // MFMA acc

// fp32 -> f16 bits RN (prep kernels / cold paths)
__device__ inline unsigned short f2h(float f) {
  return __half_as_ushort(__float2half(f));
}
// hot pack: single v_cvt_pkrtz_f16_f32 (RTZ; pre-LN data, tiny bias washes in LN)
__device__ inline unsigned pkrtz_u(float a, float b) {
  auto h = __builtin_amdgcn_cvt_pkrtz(a, b);   // __fp16 ext_vector(2)
  unsigned u; __builtin_memcpy(&u, &h, 4); return u;
}
// RN pack for h1 store
__device__ inline unsigned pack2h(float a, float b) {
  __half2 h = __floats2half2_rn(a, b);
  unsigned u; __builtin_memcpy(&u, &h, 4); return u;
}
__device__ inline __half2 u2h(unsigned u) {
  __half2 h; __builtin_memcpy(&h, &u, 4); return h;
}
__device__ inline unsigned h2u(__half2 h) {
  unsigned u; __builtin_memcpy(&u, &h, 4); return u;
}
__device__ inline void bflyh(__half2& a, int m) {
  unsigned u = (unsigned)__shfl_xor((int)h2u(a), m);
  a += u2h(u);
}

// ---------------- CSR build ----------------
__global__ void k_zero(int* p, int n) {
  int i = blockIdx.x * 256 + threadIdx.x;
  if (i < n) p[i] = 0;
}

__global__ void k_deg(const int* __restrict__ dst, int* __restrict__ deg) {
  int e = blockIdx.x * 256 + threadIdx.x;
  if (e < E_) atomicAdd(&deg[dst[e]], 1);
}

__global__ void k_scan(const int* __restrict__ deg, int* __restrict__ row_ptr,
                       float* __restrict__ inv_deg) {
  __shared__ int part[256];
  int tid = threadIdx.x;
  int base = tid * 40;
  int s = 0;
  for (int i = 0; i < 40; i++) { int idx = base + i; if (idx < N_) s += deg[idx]; }
  part[tid] = s;
  __syncthreads();
  if (tid == 0) {
    int run = 0;
    for (int i = 0; i < 256; i++) { int v = part[i]; part[i] = run; run += v; }
  }
  __syncthreads();
  int run = part[tid];
  for (int i = 0; i < 40; i++) {
    int idx = base + i;
    if (idx < N_) {
      row_ptr[idx] = run;
      int d = deg[idx];
      run += d;
      inv_deg[idx] = 1.0f / fmaxf((float)d, 1.0f);
    } else if (idx == N_) {
      row_ptr[N_] = run;
    }
  }
}

__global__ void k_fill(const int* __restrict__ src, const int* __restrict__ dst,
                       const int* __restrict__ row_ptr, int* __restrict__ cursor,
                       int* __restrict__ col) {
  int e = blockIdx.x * 256 + threadIdx.x;
  if (e < E_) {
    int d = dst[e];
    int p = atomicAdd(&cursor[d], 1);
    col[row_ptr[d] + p] = src[e];
  }
}

// ---------------- weight prep (f16 fragments) ----------------
// sage2 MFMA B-fragments: j = w*16+(l&15), k = ks*32+(l>>4)*8+q (same k-map as A).
__global__ void k_prepw(const float* __restrict__ W2l, const float* __restrict__ W2r,
                        unsigned short* __restrict__ Wbf) {
  int idx = blockIdx.x * 256 + threadIdx.x;   // 8192 total
  if (idx >= 4 * 4 * 64 * 8) return;
  int q  = idx & 7;
  int l  = (idx >> 3) & 63;
  int ks = (idx >> 9) & 3;
  int w  = idx >> 11;
  int j = w * 16 + (l & 15);
  int k = ks * 32 + ((l >> 4) * 8) + q;
  float v = (k < 64) ? W2l[j * 64 + k] : W2r[j * 64 + (k - 64)];
  Wbf[idx] = f2h(v);
}

// sage1 B-fragments: k in [0,32): 0:16 = W1l cols, 16:32 = W1r cols.
__global__ void k_prepw1(const float* __restrict__ W1l, const float* __restrict__ W1r,
                         unsigned short* __restrict__ Wb1) {
  int idx = blockIdx.x * 256 + threadIdx.x;   // 2048 total
  if (idx >= 4 * 64 * 8) return;
  int q = idx & 7;
  int l = (idx >> 3) & 63;
  int w = idx >> 9;
  int j = w * 16 + (l & 15);
  int k = ((l >> 4) * 8) + q;
  float v = (k < 16) ? W1l[j * 16 + k] : W1r[j * 16 + (k - 16)];
  Wb1[idx] = f2h(v);
}

// ---------------- SAGE layer 1, MFMA Phase B, f16 ----------------
// Phase A: lane = (node[2] | eo2[2] | fq2[2]); float4 gathers; staged row_ptr;
// batch-2 rounds (phantom via zero-row pointer). Z1b[64][40] f16.
__launch_bounds__(256, 8)
__global__ void k_sage1t(const float* __restrict__ x, const int* __restrict__ row_ptr,
                         const int* __restrict__ col, const float* __restrict__ inv_deg,
                         const unsigned short* __restrict__ Wb1, const float* __restrict__ b1,
                         const float* __restrict__ g1, const float* __restrict__ be1,
                         unsigned short* __restrict__ h1, const float* __restrict__ zrow,
                         int bt0, int CH, int swz) {
  __shared__ __align__(16) unsigned short ZU[64 * 136];   // f16 Z1b[64][40] / f32 Zf[64][68]
  __shared__ float red[2][4][64];
  unsigned short* Z1b = ZU;
  float* Zf = (float*)ZU;
  int i = blockIdx.x;
  int btl, chunk;
  if (swz) {  // pin all blocks of one bt to one XCD
    int xcd = i & 7; int j = i >> 3; int per = CH >> 3;
    btl = xcd * per + j / PB_; chunk = j % PB_;
  } else {
    btl = i / PB_; chunk = i % PB_;
  }
  int bt = bt0 + btl;
  size_t xbase = (size_t)bt * (N_ * F_);
  int tid = threadIdx.x;
  int w = __builtin_amdgcn_readfirstlane(tid >> 6);
  int lane = tid & 63;
  int n0 = chunk * 64;
  int node = lane >> 4;        // 0..3
  int eo2 = (lane >> 2) & 3;   // edge slot
  int fq2 = lane & 3;          // feat group (float4)
  const float4* x4b = (const float4*)(x + xbase);   // node row = 4 float4
  const float4* z4 = (const float4*)zrow;

  // ---- stage row_ptr / deg / inv_deg for this wave's 16 nodes ----
  int nloc = n0 + w * 16 + (lane & 15);
  int rpA = 0, dS = 0; float ivS = 0.f;
  if (nloc < N_) { rpA = row_ptr[nloc]; dS = row_ptr[nloc + 1] - rpA; ivS = inv_deg[nloc]; }

  // ---- Phase A ----
  for (int p = 0; p < 4; ++p) {
    int mA = w * 16 + p * 4;
    int nA = n0 + mA;
    int s0My   = __shfl(rpA, p * 4 + node);
    int dMy    = __shfl(dS,  p * 4 + node);
    float ivMy = __shfl(ivS, p * 4 + node);
    int dcMy = dMy > 64 ? 64 : dMy;
    int tmx = max(dcMy, __shfl_xor(dcMy, 16));
    int mx  = max(tmx, __shfl_xor(tmx, 32));
    int rounds = (mx + 3) >> 2;
    // stage my node's col list: 4 regs x 16 entries
    int pos = lane & 15;
    int c0r = (pos      < dMy) ? col[s0My + pos]      : 0;
    int c1r = (pos + 16 < dMy) ? col[s0My + pos + 16] : 0;
    int c2r = (pos + 32 < dMy) ? col[s0My + pos + 32] : 0;
    int c3r = (pos + 48 < dMy) ? col[s0My + pos + 48] : 0;
    float4 a = {0.f, 0.f, 0.f, 0.f};
#define S1B(REG, BASE, RR)                                            \
    {                                                                 \
      int idx = eo2 + 4 * (RR);                                       \
      int s = __shfl(REG, (lane & 48) | (idx - (BASE)));              \
      const float4* bp = (idx < dcMy) ? (x4b + (size_t)s * 4) : z4;   \
      float4 v = bp[fq2];                                             \
      a.x += v.x; a.y += v.y; a.z += v.z; a.w += v.w;                 \
    }
    int rounds2 = (rounds + 1) & ~1;
    int r = 0;
    for (; r < rounds2 && r < 4;  r += 2) { S1B(c0r, 0, r)  S1B(c0r, 0, r + 1) }
    for (; r < rounds2 && r < 8;  r += 2) { S1B(c1r, 16, r) S1B(c1r, 16, r + 1) }
    for (; r < rounds2 && r < 12; r += 2) { S1B(c2r, 32, r) S1B(c2r, 32, r + 1) }
    for (; r < rounds2; r += 2)           { S1B(c3r, 48, r) S1B(c3r, 48, r + 1) }
#undef S1B
    if (dMy > 64) {
      for (int e = s0My + 64; e < s0My + dMy; ++e) {
        if (eo2 == 0) {
          float4 v = x4b[(size_t)col[e] * 4 + fq2];
          a.x += v.x; a.y += v.y; a.z += v.z; a.w += v.w;
        }
      }
    }
    // butterfly over eo2 (lane bits 2-3)
    a.x += __shfl_xor(a.x, 4);  a.y += __shfl_xor(a.y, 4);
    a.z += __shfl_xor(a.z, 4);  a.w += __shfl_xor(a.w, 4);
    a.x += __shfl_xor(a.x, 8);  a.y += __shfl_xor(a.y, 8);
    a.z += __shfl_xor(a.z, 8);  a.w += __shfl_xor(a.w, 8);
    if (eo2 == 0) {
      uint2 pk;
      pk.x = pkrtz_u(a.x * ivMy, a.y * ivMy);
      pk.y = pkrtz_u(a.z * ivMy, a.w * ivMy);
      *(uint2*)&Z1b[(mA + node) * 40 + fq2 * 4] = pk;          // agg: k = fq2*4..+3
    } else if (eo2 == 1) {
      int nS = nA + node;
      float4 sv = {0.f, 0.f, 0.f, 0.f};
      if (nS < N_) sv = x4b[(size_t)nS * 4 + fq2];
      uint2 pk;
      pk.x = pkrtz_u(sv.x, sv.y);
      pk.y = pkrtz_u(sv.z, sv.w);
      *(uint2*)&Z1b[(mA + node) * 40 + 16 + fq2 * 4] = pk;     // self: k = 16+..
    }
  }
  __syncthreads();

  // ---- Phase B: one f16 MFMA per node-tile. Wave w owns j in [16w,16w+16). ----
  int g = lane >> 4, c = lane & 15;
  float bj = b1[w * 16 + c];
  f32x4_t accf[4];
#pragma unroll
  for (int mt = 0; mt < 4; ++mt) accf[mt] = (f32x4_t){bj, bj, bj, bj};
  f16x8_t bfr = ((const f16x8_t*)Wb1)[w * 64 + lane];
#pragma unroll
  for (int mt = 0; mt < 4; ++mt) {
    const f16x8_t* ap = (const f16x8_t*)&Z1b[(mt * 16 + c) * 40 + g * 8];
    accf[mt] = __builtin_amdgcn_mfma_f32_16x16x32_f16(*ap, bfr, accf[mt], 0, 0, 0);
  }
  __syncthreads();   // all waves done reading Z1b before aliased fp32 writes

  // C layout (HW-verified, dtype-independent): col = lane&15, row = 4*(lane>>4)+reg.
#pragma unroll
  for (int mt = 0; mt < 4; ++mt) {
#pragma unroll
    for (int q = 0; q < 4; ++q) {
      int nodeq = mt * 16 + g * 4 + q;
      Zf[nodeq * 68 + w * 16 + c] = accf[mt][q];
    }
  }
  __syncthreads();

  // ---- Epilogue: lane = node m; wave w owns j-quarter [16w,16w+16) ----
  int m = lane;
  const float* zr = Zf + m * 68 + w * 16;
  float4 z0 = *(const float4*)(zr + 0);
  float4 z1 = *(const float4*)(zr + 4);
  float4 z2 = *(const float4*)(zr + 8);
  float4 z3 = *(const float4*)(zr + 12);
  float acc[16];
  acc[0] = z0.x; acc[1] = z0.y; acc[2] = z0.z; acc[3] = z0.w;
  acc[4] = z1.x; acc[5] = z1.y; acc[6] = z1.z; acc[7] = z1.w;
  acc[8] = z2.x; acc[9] = z2.y; acc[10] = z2.z; acc[11] = z2.w;
  acc[12] = z3.x; acc[13] = z3.y; acc[14] = z3.z; acc[15] = z3.w;

  // ---- LayerNorm across j (single-pass: sum + sumsq) ----
  float s1 = 0.f, s2 = 0.f;
#pragma unroll
  for (int jj = 0; jj < 16; ++jj) { s1 += acc[jj]; s2 += acc[jj] * acc[jj]; }
  red[0][w][m] = s1;
  red[1][w][m] = s2;
  __syncthreads();
  float mu = (red[0][0][m] + red[0][1][m] + red[0][2][m] + red[0][3][m]) * (1.f / 64.f);
  float ex2 = (red[1][0][m] + red[1][1][m] + red[1][2][m] + red[1][3][m]) * (1.f / 64.f);
  float var = fmaxf(ex2 - mu * mu, 0.f);
  float rs = rsqrtf(var + EPS_);

  // ---- relu + f16 pack + store (h1 has NR_=N+1 rows; row N_ = phantom) ----
  int nAbs = n0 + m;
  unsigned short* dst = h1 + ((size_t)btl * NR_ + nAbs) * HG_ + w * 16;
  if (nAbs < N_) {
#pragma unroll
    for (int jj = 0; jj < 16; ++jj)
      acc[jj] = fmaxf((acc[jj] - mu) * rs * g1[w * 16 + jj] + be1[w * 16 + jj], 0.f);
    uint4 pa, pb;
    pa.x = pack2h(acc[0], acc[1]);  pa.y = pack2h(acc[2], acc[3]);
    pa.z = pack2h(acc[4], acc[5]);  pa.w = pack2h(acc[6], acc[7]);
    pb.x = pack2h(acc[8], acc[9]);  pb.y = pack2h(acc[10], acc[11]);
    pb.z = pack2h(acc[12], acc[13]); pb.w = pack2h(acc[14], acc[15]);
    *(uint4*)dst = pa;
    *(uint4*)(dst + 8) = pb;
  } else if (nAbs == N_) {
    uint4 zz = {0, 0, 0, 0};
    *(uint4*)dst = zz;
    *(uint4*)(dst + 8) = zz;
  }
}

// ---------------- SAGE layer 2 (f16 in), MFMA Phase B ----------------
// Phase A: lane = (nsel[1] | eo2[2] | fq3[3]); uint4 (8 f16) gathers; staged
// row_ptr; ALL col lists pre-staged in 16 regs; batch-2 rounds (phantom row);
// packed __half2 accumulate. Zb[64][136] f16, aliased fp32 after MFMA.
__launch_bounds__(256, 8)
__global__ void k_sage2t(const unsigned short* __restrict__ h1, const int* __restrict__ row_ptr,
                         const int* __restrict__ col, const float* __restrict__ inv_deg,
                         const unsigned short* __restrict__ Wbf, const float* __restrict__ b2,
                         const float* __restrict__ g2, const float* __restrict__ be2,
                         float* __restrict__ Hsum, int bt0, int CH, int swz) {
  __shared__ __align__(16) unsigned short Zb[64 * 136];   // f16 / aliased fp32
  __shared__ float red[2][4][64];
  float* Zf = (float*)Zb;   // fp32 view, stride 68 floats
  int i = blockIdx.x;
  int btl, chunk;
  if (swz) {
    int xcd = i & 7; int j = i >> 3; int per = CH >> 3;
    btl = xcd * per + j / PB_; chunk = j % PB_;
  } else {
    btl = i / PB_; chunk = i % PB_;
  }
  int bt = bt0 + btl;
  int b = bt / T_, t = bt % T_;
  const char* h8c = (const char*)(h1 + (size_t)btl * (NR_ * HG_));  // row = 128 B
  int tid = threadIdx.x;
  int w = __builtin_amdgcn_readfirstlane(tid >> 6);
  int lane = tid & 63;
  int n0 = chunk * 64;
  int nsel = lane >> 5;        // 0/1: which of the pair's nodes
  int eo2 = (lane >> 3) & 3;   // 4 edge slots
  int fq3 = lane & 7;          // 8 feat groups (uint4 = 8 f16)
  unsigned foff = (unsigned)fq3 * 16;
  int pos = lane & 31;

  // ---- stage row_ptr / deg / inv_deg for this wave's 16 nodes ----
  int nloc = n0 + w * 16 + (lane & 15);
  int rpA = 0, dS = 0; float ivS = 0.f;
  if (nloc < N_) { rpA = row_ptr[nloc]; dS = row_ptr[nloc + 1] - rpA; ivS = inv_deg[nloc]; }

  // ---- pre-stage ALL 8 p-iters' col lists (16 independent loads in flight) ----
  int cp0[8], cp1[8];
#pragma unroll
  for (int p = 0; p < 8; ++p) {
    int s0 = __shfl(rpA, p * 2 + nsel);
    int d  = __shfl(dS,  p * 2 + nsel);
    cp0[p] = (pos      < d) ? col[s0 + pos]      : N_;
    cp1[p] = (pos + 32 < d) ? col[s0 + pos + 32] : N_;
  }

  // ---- Phase A ----
#pragma unroll
  for (int p = 0; p < 8; ++p) {
    int mA = w * 16 + p * 2;
    int s0My   = __shfl(rpA, p * 2 + nsel);
    int dMy    = __shfl(dS,  p * 2 + nsel);
    float ivMy = __shfl(ivS, p * 2 + nsel);
    int dcMy = dMy > 64 ? 64 : dMy;
    int mx = max(dcMy, __shfl_xor(dcMy, 32));
    int rounds = (mx + 3) >> 2;
    __half2 a0 = __float2half2_rn(0.f), a1 = a0, a2 = a0, a3 = a0;
#define S2B(PREG, BASE, RR)                                             \
    {                                                                   \
      int idx = eo2 + 4 * (RR);                                         \
      int s = __shfl(PREG, (lane & 32) | (idx - (BASE)));               \
      uint4 v = *(const uint4*)(h8c + (((unsigned)s << 7) + foff));     \
      a0 += u2h(v.x); a1 += u2h(v.y); a2 += u2h(v.z); a3 += u2h(v.w);   \
    }
    int rounds2 = (rounds + 1) & ~1;
    int r = 0;
    for (; r < rounds2 && r < 8; r += 2) { S2B(cp0[p], 0, r)  S2B(cp0[p], 0, r + 1) }
    for (; r < rounds2; r += 2)          { S2B(cp1[p], 32, r) S2B(cp1[p], 32, r + 1) }
#undef S2B
    if (dMy > 64) {
      for (int e = s0My + 64; e < s0My + dMy; ++e) {
        if (eo2 == 0) {
          uint4 v = *(const uint4*)(h8c + (((unsigned)col[e] << 7) + foff));
          a0 += u2h(v.x); a1 += u2h(v.y); a2 += u2h(v.z); a3 += u2h(v.w);
        }
      }
    }
    // butterfly over eo2 (lane bits 3-4), packed f16
    bflyh(a0, 8);  bflyh(a1, 8);  bflyh(a2, 8);  bflyh(a3, 8);
    bflyh(a0, 16); bflyh(a1, 16); bflyh(a2, 16); bflyh(a3, 16);
    if (eo2 == 0) {
      __half2 ivh = __float2half2_rn(ivMy);
      uint4 pk;
      pk.x = h2u(a0 * ivh); pk.y = h2u(a1 * ivh);
      pk.z = h2u(a2 * ivh); pk.w = h2u(a3 * ivh);
      *(uint4*)&Zb[(mA + nsel) * 136 + fq3 * 8] = pk;            // agg: k = fq3*8..+7
    } else if (eo2 == 1) {
      int nA = n0 + mA;
      int nS = nA + nsel;
      int nSc = nS < N_ ? nS : N_;
      uint4 sv = *(const uint4*)(h8c + (((unsigned)nSc << 7) + foff));
      *(uint4*)&Zb[(mA + nsel) * 136 + 64 + fq3 * 8] = sv;       // self: k = 64+..
    }
  }
  __syncthreads();

  // ---- Phase B: f16 MFMA. Wave w owns output features j in [16w, 16w+16). ----
  int g = lane >> 4, c = lane & 15;
  const f16x8_t* Wb8 = (const f16x8_t*)Wbf;
  float bj = b2[w * 16 + c];
  f32x4_t accf[4];
#pragma unroll
  for (int mt = 0; mt < 4; ++mt) accf[mt] = (f32x4_t){bj, bj, bj, bj};
#pragma unroll
  for (int ks = 0; ks < 4; ++ks) {
    f16x8_t bfr = Wb8[(w * 4 + ks) * 64 + lane];
#pragma unroll
    for (int mt = 0; mt < 4; ++mt) {
      const f16x8_t* ap = (const f16x8_t*)&Zb[(mt * 16 + c) * 136 + ks * 32 + g * 8];
      accf[mt] = __builtin_amdgcn_mfma_f32_16x16x32_f16(*ap, bfr, accf[mt], 0, 0, 0);
    }
  }
  __syncthreads();   // all waves done reading Zb before aliased fp32 writes

  // C layout (HW-verified): col = lane&15, row = 4*(lane>>4)+reg.
#pragma unroll
  for (int mt = 0; mt < 4; ++mt) {
#pragma unroll
    for (int q = 0; q < 4; ++q) {
      int nodeq = mt * 16 + g * 4 + q;
      Zf[nodeq * 68 + w * 16 + c] = accf[mt][q];
    }
  }
  __syncthreads();

  // ---- Epilogue: lane = node m; wave w owns j-quarter [16w,16w+16) ----
  int m = lane;
  float* zr = Zf + m * 68 + w * 16;
  float4 z0 = *(const float4*)(zr + 0);
  float4 z1 = *(const float4*)(zr + 4);
  float4 z2 = *(const float4*)(zr + 8);
  float4 z3 = *(const float4*)(zr + 12);
  float acc[16];
  acc[0] = z0.x; acc[1] = z0.y; acc[2] = z0.z; acc[3] = z0.w;
  acc[4] = z1.x; acc[5] = z1.y; acc[6] = z1.z; acc[7] = z1.w;
  acc[8] = z2.x; acc[9] = z2.y; acc[10] = z2.z; acc[11] = z2.w;
  acc[12] = z3.x; acc[13] = z3.y; acc[14] = z3.z; acc[15] = z3.w;

  // ---- LayerNorm across j (single-pass: sum + sumsq) ----
  float s1 = 0.f, s2 = 0.f;
#pragma unroll
  for (int jj = 0; jj < 16; ++jj) { s1 += acc[jj]; s2 += acc[jj] * acc[jj]; }
  red[0][w][m] = s1;
  red[1][w][m] = s2;
  __syncthreads();
  float mu = (red[0][0][m] + red[0][1][m] + red[0][2][m] + red[0][3][m]) * (1.f / 64.f);
  float ex2 = (red[1][0][m] + red[1][1][m] + red[1][2][m] + red[1][3][m]) * (1.f / 64.f);
  float var = fmaxf(ex2 - mu * mu, 0.f);
  float rs = rsqrtf(var + EPS_);

  // ---- relu, write back in-place (lane-exclusive region: no hazard) ----
  bool okm = (n0 + m) < N_;
#pragma unroll
  for (int jj = 0; jj < 16; ++jj) {
    float hv = fmaxf((acc[jj] - mu) * rs * g2[w * 16 + jj] + be2[w * 16 + jj], 0.f);
    acc[jj] = okm ? hv : 0.f;
  }
  float4 o0 = {acc[0], acc[1], acc[2], acc[3]};
  float4 o1 = {acc[4], acc[5], acc[6], acc[7]};
  float4 o2 = {acc[8], acc[9], acc[10], acc[11]};
  float4 o3 = {acc[12], acc[13], acc[14], acc[15]};
  *(float4*)(zr + 0) = o0;  *(float4*)(zr + 4) = o1;
  *(float4*)(zr + 8) = o2;  *(float4*)(zr + 12) = o3;
  __syncthreads();

  // ---- column sums: lane = feature j; wave w sums rows [16w,16w+16) ----
  float cs = 0.f;
#pragma unroll
  for (int ii = 0; ii < 16; ++ii) cs += Zf[(w * 16 + ii) * 68 + lane];
  red[0][w][lane] = cs;
  __syncthreads();
  if (w == 0) {
    float tot = red[0][0][lane] + red[0][1][lane] + red[0][2][lane] + red[0][3][lane];
    atomicAdd(&Hsum[(t * B_ + b) * HG_ + lane], tot);
  }
}

// ---------------- GRU input precompute: GI[t][b][384] ----------------
__global__ void k_gi(const float* __restrict__ Hsum, const float* __restrict__ W_ih,
                     const float* __restrict__ b_ih, float* __restrict__ GI) {
  __shared__ float xv[64];
  int tb = blockIdx.x;
  int tid = threadIdx.x;
  if (tid < 64) xv[tid] = Hsum[tb * 64 + tid] * (1.0f / (float)N_);
  __syncthreads();
  float g = b_ih[tid];
  const float4* W4 = (const float4*)(W_ih + tid * 64);
  const float4* x4 = (const float4*)xv;
#pragma unroll
  for (int q = 0; q < 16; q++) {
    float4 w = W4[q], xq = x4[q];
    g = fmaf(xq.x, w.x, g); g = fmaf(xq.y, w.y, g);
    g = fmaf(xq.z, w.z, g); g = fmaf(xq.w, w.w, g);
  }
  GI[tb * 384 + tid] = g;
}

// ---------------- sequential GRU + head; one block per batch ----------------
__global__ void k_gru(const float* __restrict__ GI, const float* __restrict__ W_hh,
                      const float* __restrict__ b_hh, const float* __restrict__ Wh,
                      const float* __restrict__ bh, float* __restrict__ out) {
  __shared__ float hL[128];
  __shared__ float ghL[384];
  __shared__ float red[128];
  int b = blockIdx.x, tid = threadIdx.x;
  if (tid < 128) hL[tid] = 0.f;
  float bhh = b_hh[tid];
  const float4* W4 = (const float4*)(W_hh + tid * 128);
  for (int t = 0; t < T_; ++t) {
    __syncthreads();
    float g = bhh;
    const float4* h4 = (const float4*)hL;
#pragma unroll
    for (int q = 0; q < 32; q++) {
      float4 w = W4[q], hv = h4[q];
      g = fmaf(hv.x, w.x, g); g = fmaf(hv.y, w.y, g);
      g = fmaf(hv.z, w.z, g); g = fmaf(hv.w, w.w, g);
    }
    ghL[tid] = g;
    __syncthreads();
    float hnew = 0.f;
    if (tid < 128) {
      const float* gi = GI + (t * B_ + b) * 384;
      float rr = 1.f / (1.f + expf(-(gi[tid] + ghL[tid])));
      float zz = 1.f / (1.f + expf(-(gi[128 + tid] + ghL[128 + tid])));
      float nn = tanhf(gi[256 + tid] + rr * ghL[256 + tid]);
      hnew = (1.f - zz) * nn + zz * hL[tid];
    }
    __syncthreads();
    if (tid < 128) hL[tid] = hnew;
  }
  __syncthreads();
  if (tid < 128) red[tid] = hL[tid] * Wh[tid];
  __syncthreads();
  if (tid == 0) {
    float s = bh[0];
    for (int k = 0; k < 128; k++) s += red[k];
    out[b] = s;
  }
}

extern "C" void kernel_launch(void* const* d_in, const int* in_sizes, int n_in,
                              void* d_out, int out_size, void* d_ws, size_t ws_size,
                              hipStream_t stream) {
  const float* x    = (const float*)d_in[0];
  const int*   ei   = (const int*)d_in[1];
  const float* W1l  = (const float*)d_in[2];
  const float* b1   = (const float*)d_in[3];
  const float* W1r  = (const float*)d_in[4];
  const float* g1   = (const float*)d_in[5];
  const float* be1  = (const float*)d_in[6];
  const float* W2l  = (const float*)d_in[7];
  const float* b2   = (const float*)d_in[8];
  const float* W2r  = (const float*)d_in[9];
  const float* g2   = (const float*)d_in[10];
  const float* be2  = (const float*)d_in[11];
  const float* W_ih = (const float*)d_in[12];
  const float* W_hh = (const float*)d_in[13];
  const float* b_ih = (const float*)d_in[14];
  const float* b_hh = (const float*)d_in[15];
  const float* Wh   = (const float*)d_in[16];
  const float* bh   = (const float*)d_in[17];
  float* out = (float*)d_out;

  char* ws = (char*)d_ws;
  size_t off = 0;
  auto alloc = [&](size_t bytes) { void* p = ws + off; off += (bytes + 255) & ~(size_t)255; return p; };
  int*   deg     = (int*)alloc((size_t)N_ * 4);
  int*   row_ptr = (int*)alloc((size_t)(N_ + 1) * 4);
  int*   cursor  = (int*)alloc((size_t)N_ * 4);
  int*   col     = (int*)alloc((size_t)E_ * 4);
  float* ivd     = (float*)alloc((size_t)N_ * 4);
  float* Hsum    = (float*)alloc((size_t)BT_ * HG_ * 4);
  float* GI      = (float*)alloc((size_t)BT_ * 384 * 4);
  unsigned short* Wbf = (unsigned short*)alloc((size_t)4 * 4 * 64 * 8 * 2);  // sage2 f16 B-frags
  unsigned short* Wb1 = (unsigned short*)alloc((size_t)4 * 64 * 8 * 2);      // sage1 f16 B-frags
  float* zrowp   = (float*)alloc(256);   // 128B zero row (+ pad), zeroed by k_zero
  size_t fixed = off;
  unsigned short* h1 = (unsigned short*)(ws + off);

  size_t cap = (ws_size > fixed) ? (ws_size - fixed) : 0;
  int CH = (int)(cap / ((size_t)NR_ * HG_ * 2));   // f16 h1, N+1 rows per bt
  if (CH > 64) CH = 64;    // keep chunk working set inside the 256MB L3
  if (CH >= 8) CH &= ~7;   // multiple of 8 for XCD swizzle
  if (CH < 1) CH = 1;

  int zn = (int)(fixed / 4);
  k_zero<<<(zn + 255) / 256, 256, 0, stream>>>((int*)ws, zn);

  const int* srcp = ei;
  const int* dstp = ei + E_;
  k_deg<<<(E_ + 255) / 256, 256, 0, stream>>>(dstp, deg);
  k_scan<<<1, 256, 0, stream>>>(deg, row_ptr, ivd);
  k_fill<<<(E_ + 255) / 256, 256, 0, stream>>>(srcp, dstp, row_ptr, cursor, col);
  k_prepw<<<32, 256, 0, stream>>>(W2l, W2r, Wbf);
  k_prepw1<<<8, 256, 0, stream>>>(W1l, W1r, Wb1);

  for (int bt0 = 0; bt0 < BT_; bt0 += CH) {
    int c = BT_ - bt0 < CH ? BT_ - bt0 : CH;
    int swz = (c % 8 == 0) ? 1 : 0;
    k_sage1t<<<c * PB_, 256, 0, stream>>>(x, row_ptr, col, ivd, Wb1, b1, g1, be1,
                                          h1, zrowp, bt0, c, swz);
    k_sage2t<<<c * PB_, 256, 0, stream>>>(h1, row_ptr, col, ivd, Wbf, b2, g2, be2,
                                          Hsum, bt0, c, swz);
  }
  k_gi<<<BT_, 384, 0, stream>>>(Hsum, W_ih, b_ih, GI);
  k_gru<<<B_, 384, 0, stream>>>(GI, W_hh, b_hh, Wh, bh, out);
}